// Round 8
// baseline (1140.461 us; speedup 1.0000x reference)
//
#include <hip/hip_runtime.h>
#include <math.h>

// PointWiseDecoder2DSimple on MI355X (gfx950)
// b=8, nq=nc=4096, LATENT=256, HEADS=4, DH=256, INNER=1024.
// R8: revert to R6 LDS-staged counted-vmcnt structure (R7 no-LDS falsified);
// occupancy 2->3 blocks/CU via __launch_bounds__(256,3); coalesced Q-store
// via TB LDS bounce in gemm_fuse<1>; MODE-1 alias-race barrier added.

typedef unsigned short u16;
typedef __attribute__((ext_vector_type(4))) float f32x4;
typedef __attribute__((ext_vector_type(8))) short s16x8;
typedef __attribute__((ext_vector_type(8))) unsigned short u16x8;
typedef __attribute__((ext_vector_type(4))) unsigned short u16x4;

#define LOG2_1E4_D64 0.20762050593046013f  // log2(10000)/64

#define VMCNT(n) do{ asm volatile("s_waitcnt vmcnt(" #n ")" ::: "memory"); \
                     __builtin_amdgcn_sched_barrier(0); }while(0)
#define BARRIER() do{ __builtin_amdgcn_s_barrier(); \
                      __builtin_amdgcn_sched_barrier(0); }while(0)

__device__ __forceinline__ u16 f2b(float f){
  union { float f; unsigned u; } v; v.f = f;
  unsigned u = v.u;
  u += 0x7FFFu + ((u >> 16) & 1u);
  return (u16)(u >> 16);
}
__device__ __forceinline__ float b2f(u16 b){
  union { unsigned u; float f; } v; v.u = ((unsigned)b) << 16; return v.f;
}
__device__ __forceinline__ float gelu_f(float x){
  return 0.5f * x * (1.0f + erff(x * 0.7071067811865475f));
}

#if __has_builtin(__builtin_amdgcn_global_load_lds)
#define HAVE_GLL 1
typedef const __attribute__((address_space(1))) void* as1cv;
typedef __attribute__((address_space(3))) void* as3v;
__device__ __forceinline__ void gload16(const void* g, void* l){
  __builtin_amdgcn_global_load_lds((as1cv)g, (as3v)l, 16, 0, 0);
}
#else
#define HAVE_GLL 0
#endif

// ---------------- merged prep: z-cast + 9 weight transposes + fourier ----------------

struct PrepArgs {
  const float* z; u16* Zb;
  const float* qp; const float* Bff; u16* X0;
  const float* W[9]; u16* Wt[9];
  int K[9]; int N[9]; int boff[10];
  int castB, tcB;
};
__global__ __launch_bounds__(256) void k_prep(PrepArgs a){
  int b = blockIdx.x, tid = threadIdx.x;
  if (b < a.castB){
    long i = (long)b * 256 + tid;
    float4 f = ((const float4*)a.z)[i];
    u16x4 o = { f2b(f.x), f2b(f.y), f2b(f.z), f2b(f.w) };
    ((u16x4*)a.Zb)[i] = o;
  } else if (b < a.castB + a.tcB){
    int bb = b - a.castB;
    int w = 0;
    while (bb >= a.boff[w+1]) w++;
    int idx = (bb - a.boff[w]) * 256 + tid;
    int K = a.K[w], N = a.N[w];
    int n = idx / K, k = idx - n * K;
    a.Wt[w][idx] = f2b(a.W[w][(long)k * N + n]);
  } else {
    int bb = b - a.castB - a.tcB;
    long r = (long)bb * 2 + (tid >> 7);
    int j = tid & 127;
    float qx = a.qp[r*2], qy = a.qp[r*2+1];
    float ff = 6.283185307179586f * (qx * a.Bff[j] + qy * a.Bff[128 + j]);
    a.X0[r*256 + j]       = f2b(sinf(ff));
    a.X0[r*256 + 128 + j] = f2b(cosf(ff));
  }
}

// split-K reduce: kvT[i] = bf16(sum_sp p[sp][i]), SPL=4
__global__ __launch_bounds__(256) void k_red(const float* __restrict__ p, u16* __restrict__ out, long stride){
  long i = (long)blockIdx.x * 256 + threadIdx.x;
  f32x4 s = ((const f32x4*)p)[i];
  s += ((const f32x4*)(p + stride))[i];
  s += ((const f32x4*)(p + 2*stride))[i];
  s += ((const f32x4*)(p + 3*stride))[i];
  u16x4 o = { f2b(s[0]), f2b(s[1]), f2b(s[2]), f2b(s[3]) };
  ((u16x4*)out)[i] = o;
}

// final head: out = H2 @ Wh3 + bh3  (N=3, K=128), fp32
__global__ __launch_bounds__(256) void k_final(const u16* __restrict__ H2, const float* __restrict__ Wh3,
                                               const float* __restrict__ bh3, float* __restrict__ out){
  long r = (long)blockIdx.x * 256 + threadIdx.x;
  float a0 = bh3[0], a1 = bh3[1], a2 = bh3[2];
  const u16x8* hrow = (const u16x8*)(H2 + r*128);
#pragma unroll
  for (int c8 = 0; c8 < 16; c8++){
    u16x8 hv = hrow[c8];
#pragma unroll
    for (int e = 0; e < 8; e++){
      float f = b2f(hv[e]);
      int k = c8*8 + e;
      a0 += f * Wh3[k*3];
      a1 += f * Wh3[k*3+1];
      a2 += f * Wh3[k*3+2];
    }
  }
  out[r*3] = a0; out[r*3+1] = a1; out[r*3+2] = a2;
}

// ---------------- fused projection GEMM: one head per block-x ----------------
// C[128x256] = A[128,256] * Bh[256,256]^T  then per MODE:
//   0: KV combined — x<4: K-head (rotary+norm+T-store), x>=4: V-head (norm+T-store)
//   1: Q — rotary + coalesced store [n][x*256+d] via TB bounce
// Pipelined staging (counted vmcnt(6), 2-deep), both-sides XOR swizzle.

template<int MODE>
__global__ __launch_bounds__(256, 3)
void gemm_fuse(const u16* __restrict__ A, const u16* __restrict__ Bw,
               u16* __restrict__ outK, u16* __restrict__ outV,
               const float* __restrict__ pos){
  __shared__ char smem[49152];
  u16* AsB = (u16*)smem;            // [2][128*32]
  u16* BsB = (u16*)(smem + 16384);  // [2][256*32]

  int tid  = threadIdx.x;
  int lane = tid & 63;
  int wave = tid >> 6;
  int wm = (wave & 1) << 6;
  int wn = (wave >> 1) << 7;
  int whalf = wave >> 1;
  int yb = blockIdx.x;
  int h  = yb & 3;
  bool isK = (MODE == 1) || (yb < 4);
  long m0 = (long)blockIdx.y * 128;

  int r15 = lane & 15;
  int cc  = lane >> 4;
  int fsw = (cc ^ ((r15 >> 1) & 3)) * 8;              // read-side swizzle
  const u16* Bh = Bw + (long)yb * 65536;

  f32x4 acc[4][8];
#pragma unroll
  for (int i = 0; i < 4; i++)
#pragma unroll
    for (int j = 0; j < 8; j++)
      acc[i][j] = f32x4{0.f, 0.f, 0.f, 0.f};

#if HAVE_GLL
  int srow  = lane >> 2;
  int scolS = ((lane & 3) ^ ((lane >> 3) & 3)) * 8;   // pre-swizzled global source
  int aRow[2], bRow[4];
  const u16 *gA[2], *gB[4];
#pragma unroll
  for (int t = 0; t < 2; t++){
    aRow[t] = (wave*2 + t) * 16;
    gA[t] = A + (m0 + aRow[t] + srow) * 256 + scolS;
  }
#pragma unroll
  for (int t = 0; t < 4; t++){
    bRow[t] = (wave*4 + t) * 16;
    gB[t] = Bh + (bRow[t] + srow) * 256 + scolS;
  }
  auto stage = [&](int buf, int kk){
    u16* ab = AsB + buf*4096;
    u16* bb = BsB + buf*8192;
#pragma unroll
    for (int t = 0; t < 2; t++) gload16(gA[t] + kk*32, ab + aRow[t]*32);
#pragma unroll
    for (int t = 0; t < 4; t++) gload16(gB[t] + kk*32, bb + bRow[t]*32);
  };
  auto compute = [&](int buf){
    const u16* ab = AsB + buf*4096;
    const u16* bb = BsB + buf*8192;
    s16x8 af[4], bf[8];
#pragma unroll
    for (int i = 0; i < 4; i++) af[i] = *(const s16x8*)&ab[(wm + i*16 + r15)*32 + fsw];
#pragma unroll
    for (int j = 0; j < 8; j++) bf[j] = *(const s16x8*)&bb[(wn + j*16 + r15)*32 + fsw];
#pragma unroll
    for (int i = 0; i < 4; i++)
#pragma unroll
      for (int j = 0; j < 8; j++)
        acc[i][j] = __builtin_amdgcn_mfma_f32_16x16x32_bf16(af[i], bf[j], acc[i][j], 0, 0, 0);
  };

  stage(0, 0);
  stage(1, 1);
  int cur = 0;
  for (int t = 0; t < 7; t++){
    VMCNT(6);
    BARRIER();
    compute(cur);
    __builtin_amdgcn_sched_barrier(0);
    BARRIER();
    if (t + 2 < 8) stage(cur, t + 2);
    cur ^= 1;
  }
  VMCNT(0);
  BARRIER();
  compute(cur);
#else
  int sm = tid >> 2, sc = tid & 3;
  for (int k0 = 0; k0 < 256; k0 += 32){
    u16x8 va  = *(const u16x8*)(A + (m0 + sm)*256 + sc*8 + k0);
    u16x8 va1 = *(const u16x8*)(A + (m0 + sm + 64)*256 + sc*8 + k0);
    u16x8 vb0 = *(const u16x8*)(Bh + (sm      )*256 + sc*8 + k0);
    u16x8 vb1 = *(const u16x8*)(Bh + (sm + 64 )*256 + sc*8 + k0);
    u16x8 vb2 = *(const u16x8*)(Bh + (sm + 128)*256 + sc*8 + k0);
    u16x8 vb3 = *(const u16x8*)(Bh + (sm + 192)*256 + sc*8 + k0);
    __syncthreads();
    *(u16x8*)&AsB[sm*32 + sc*8] = va;
    *(u16x8*)&AsB[(sm+64)*32 + sc*8] = va1;
    *(u16x8*)&BsB[sm*32 + sc*8] = vb0;
    *(u16x8*)&BsB[(sm+64)*32 + sc*8] = vb1;
    *(u16x8*)&BsB[(sm+128)*32 + sc*8] = vb2;
    *(u16x8*)&BsB[(sm+192)*32 + sc*8] = vb3;
    __syncthreads();
    s16x8 af[4], bf[8];
#pragma unroll
    for (int i = 0; i < 4; i++) af[i] = *(const s16x8*)&AsB[(wm + i*16 + r15)*32 + cc*8];
#pragma unroll
    for (int j = 0; j < 8; j++) bf[j] = *(const s16x8*)&BsB[(wn + j*16 + r15)*32 + cc*8];
#pragma unroll
    for (int i = 0; i < 4; i++)
#pragma unroll
      for (int j = 0; j < 8; j++)
        acc[i][j] = __builtin_amdgcn_mfma_f32_16x16x32_bf16(af[i], bf[j], acc[i][j], 0, 0, 0);
    __syncthreads();
  }
#endif

  // ---- rotary: pair acc[i][j] <-> acc[i][j+4]; axis = whalf
  if (isK){
    float invf4[4];
#pragma unroll
    for (int jl = 0; jl < 4; jl++)
      invf4[jl] = 1024.0f * exp2f(-(float)(jl*16 + r15) * LOG2_1E4_D64);
#pragma unroll
    for (int i = 0; i < 4; i++){
#pragma unroll
      for (int r = 0; r < 4; r++){
        long n = m0 + wm + i*16 + cc*4 + r;
        float p = pos[n*2 + whalf];
#pragma unroll
        for (int jl = 0; jl < 4; jl++){
          float a = p * invf4[jl];
          float s = __sinf(a), c = __cosf(a);
          float t0 = acc[i][jl][r], t1 = acc[i][jl+4][r];
          acc[i][jl][r]   = t0*c - t1*s;
          acc[i][jl+4][r] = t1*c + t0*s;
        }
      }
    }
  }

  if constexpr (MODE == 1){
    // Q: coalesced store via TB bounce (XOR swizzle, chunk-XOR + elem-permute)
    u16* TB = (u16*)smem;   // 32KB
    __syncthreads();        // staging LDS dead before alias reuse
    long rowg = m0;
#pragma unroll
    for (int p = 0; p < 2; p++){
      if ((wave & 1) == p){
#pragma unroll
        for (int i = 0; i < 4; i++)
#pragma unroll
          for (int j = 0; j < 8; j++)
#pragma unroll
            for (int r = 0; r < 4; r++){
              int nl = i*16 + cc*4 + r;
              int d  = wn + j*16 + r15;
              TB[nl*256 + (d ^ ((nl>>2)<<1))] = f2b(acc[i][j][r]);
            }
      }
      __syncthreads();
      {
        int nl = tid >> 2;
        int cb = (tid & 3) * 8;
        int sw = (nl >> 2) << 1;
        int swHi = sw & ~7, swLo = sw & 7;
        u16* orow = outK + (rowg + p*64 + nl) * 1024 + yb*256;
#pragma unroll
        for (int c8 = 0; c8 < 8; c8++){
          int cblk = cb + c8*32;
          u16x8 vv = *(const u16x8*)&TB[nl*256 + (cblk ^ swHi)];
          u16x8 ov;
#pragma unroll
          for (int e = 0; e < 8; e++) ov[e] = vv[e ^ swLo];
          *(u16x8*)(orow + cblk) = ov;
        }
      }
      __syncthreads();
    }
  } else {
    // ---- inst_norm over 256 head dims, then transposed store [mat][d][n]
    u16*   TB  = (u16*)smem;               // 32KB
    float* PS1 = (float*)(smem + 32768);
    float* PS2 = (float*)(smem + 33792);

    __syncthreads();   // all waves done with staging LDS before reuse (race fix)

#pragma unroll
    for (int i = 0; i < 4; i++){
#pragma unroll
      for (int r = 0; r < 4; r++){
        float s1 = 0.f, s2 = 0.f;
#pragma unroll
        for (int j = 0; j < 8; j++){
          float v = acc[i][j][r];
          s1 += v; s2 += v*v;
        }
#pragma unroll
        for (int m = 1; m < 16; m <<= 1){
          s1 += __shfl_xor(s1, m, 64);
          s2 += __shfl_xor(s2, m, 64);
        }
        int rowid = (wave&1)*64 + i*16 + cc*4 + r;
        if (r15 == 0){ PS1[whalf*128 + rowid] = s1; PS2[whalf*128 + rowid] = s2; }
      }
    }
    __syncthreads();
#pragma unroll
    for (int i = 0; i < 4; i++){
#pragma unroll
      for (int r = 0; r < 4; r++){
        int rowid = (wave&1)*64 + i*16 + cc*4 + r;
        float s1 = PS1[rowid] + PS1[128 + rowid];
        float s2 = PS2[rowid] + PS2[128 + rowid];
        float mu  = s1 * 0.00390625f;
        float var = s2 * 0.00390625f - mu*mu;
        float inv = 1.0f / sqrtf(var + 1e-5f);
#pragma unroll
        for (int j = 0; j < 8; j++)
          acc[i][j][r] = (acc[i][j][r] - mu) * inv;
      }
    }
    __syncthreads();

    u16* outp = isK ? outK : outV;
    int bb  = (int)(m0 >> 12);
    int nn0 = (int)(m0 & 4095);
    long matbase = ((long)(bb*4 + h) * 256) * 4096;
#pragma unroll
    for (int p = 0; p < 2; p++){
      if ((wave & 1) == p){
#pragma unroll
        for (int i = 0; i < 4; i++)
#pragma unroll
          for (int j = 0; j < 8; j++)
#pragma unroll
            for (int r = 0; r < 4; r++){
              int nl = i*16 + cc*4 + r;
              int d  = wn + j*16 + r15;
              TB[nl*256 + (d ^ ((nl>>2)<<1))] = f2b(acc[i][j][r]);
            }
      }
      __syncthreads();
      {
        int n4 = (lane & 15) * 4;
        int sw = (lane & 15) << 1;
#pragma unroll
        for (int rnd = 0; rnd < 16; rnd++){
          int d = rnd*16 + wave*4 + (lane >> 4);
          u16x4 vv;
#pragma unroll
          for (int jj = 0; jj < 4; jj++) vv[jj] = TB[(n4+jj)*256 + (d ^ sw)];
          *(u16x4*)(outp + matbase + (long)d*4096 + nn0 + p*64 + n4) = vv;
        }
      }
      __syncthreads();
    }
  }
}

// ---------------- generic GEMM: C = A[M,K] * B[N,K]^T, 128x128 tile ----------------

enum { EP_B = 0, EP_GELU = 1, EP_BIAS_GELU = 2, EP_BIAS_RESB = 3, EP_SCALE = 4,
       EP_QP_GELU = 5, EP_F32 = 6 };

struct GArgs {
  const u16* A; const u16* B;
  u16* Cb; float* Cf;
  const float* bias; const u16* res; const float* qp; const float* wtail;
  float scale;
  int M, N, K, lda, ldb, ldc, NLO;
  long sAh, sAl, sBh, sBl, sCh, sCl;
};

template<int EP>
__global__ __launch_bounds__(256, 3)
void gemm_k(GArgs g){
  int z = blockIdx.z;
  int zh = z / g.NLO, zl = z - zh * g.NLO;
  const u16* A = g.A + (long)zh * g.sAh + (long)zl * g.sAl;
  const u16* B = g.B + (long)zh * g.sBh + (long)zl * g.sBl;
  long coff = (long)zh * g.sCh + (long)zl * g.sCl;

  __shared__ u16 As[2][128*32];
  __shared__ u16 Bs[2][128*32];

  int tid  = threadIdx.x;
  int lane = tid & 63;
  int wave = tid >> 6;
  int wm = (wave & 1) << 6;
  int wn = (wave >> 1) << 6;
  long m0 = (long)blockIdx.x * 128;
  long n0 = (long)blockIdx.y * 128;

  int r15 = lane & 15;
  int cc  = lane >> 4;
  int fsw = (cc ^ ((r15 >> 1) & 3)) * 8;

  f32x4 acc[4][4];
#pragma unroll
  for (int i = 0; i < 4; i++)
#pragma unroll
    for (int j = 0; j < 4; j++)
      acc[i][j] = f32x4{0.f, 0.f, 0.f, 0.f};

#if HAVE_GLL
  int srow  = lane >> 2;
  int scolS = ((lane & 3) ^ ((lane >> 3) & 3)) * 8;
  int aRow[2];
  const u16 *gA[2], *gB[2];
#pragma unroll
  for (int t = 0; t < 2; t++){
    aRow[t] = (wave*2 + t) * 16;
    gA[t] = A + (m0 + aRow[t] + srow) * g.lda + scolS;
    gB[t] = B + (n0 + aRow[t] + srow) * g.ldb + scolS;
  }
  auto stage = [&](int buf, int kk){
#pragma unroll
    for (int t = 0; t < 2; t++){
      gload16(gA[t] + kk*32, &As[buf][aRow[t]*32]);
      gload16(gB[t] + kk*32, &Bs[buf][aRow[t]*32]);
    }
  };
  auto compute = [&](int buf){
    s16x8 af[4], bf[4];
#pragma unroll
    for (int i = 0; i < 4; i++) af[i] = *(const s16x8*)&As[buf][(wm + i*16 + r15)*32 + fsw];
#pragma unroll
    for (int i = 0; i < 4; i++) bf[i] = *(const s16x8*)&Bs[buf][(wn + i*16 + r15)*32 + fsw];
#pragma unroll
    for (int i = 0; i < 4; i++)
#pragma unroll
      for (int j = 0; j < 4; j++)
        acc[i][j] = __builtin_amdgcn_mfma_f32_16x16x32_bf16(af[i], bf[j], acc[i][j], 0, 0, 0);
  };

  int nt = g.K >> 5;
  stage(0, 0);
  stage(1, 1);
  int cur = 0;
  for (int t = 0; t < nt - 1; t++){
    VMCNT(4);
    BARRIER();
    compute(cur);
    __builtin_amdgcn_sched_barrier(0);
    BARRIER();
    if (t + 2 < nt) stage(cur, t + 2);
    cur ^= 1;
  }
  VMCNT(0);
  BARRIER();
  compute(cur);
#else
  int sm  = tid >> 2;
  int sc  = tid & 3;
  for (int k0 = 0; k0 < g.K; k0 += 32){
    u16x8 va0 = *(const u16x8*)(A + (m0 + sm )*g.lda + sc*8 + k0);
    u16x8 va1 = *(const u16x8*)(A + (m0 + sm + 64)*g.lda + sc*8 + k0);
    u16x8 vb0 = *(const u16x8*)(B + (n0 + sm )*g.ldb + sc*8 + k0);
    u16x8 vb1 = *(const u16x8*)(B + (n0 + sm + 64)*g.ldb + sc*8 + k0);
    __syncthreads();
    *(u16x8*)&As[0][sm*32 + sc*8] = va0;
    *(u16x8*)&As[0][(sm+64)*32 + sc*8] = va1;
    *(u16x8*)&Bs[0][sm*32 + sc*8] = vb0;
    *(u16x8*)&Bs[0][(sm+64)*32 + sc*8] = vb1;
    __syncthreads();
    s16x8 af[4], bf[4];
#pragma unroll
    for (int i = 0; i < 4; i++) af[i] = *(const s16x8*)&As[0][(wm + i*16 + r15)*32 + cc*8];
#pragma unroll
    for (int i = 0; i < 4; i++) bf[i] = *(const s16x8*)&Bs[0][(wn + i*16 + r15)*32 + cc*8];
#pragma unroll
    for (int i = 0; i < 4; i++)
#pragma unroll
      for (int j = 0; j < 4; j++)
        acc[i][j] = __builtin_amdgcn_mfma_f32_16x16x32_bf16(af[i], bf[j], acc[i][j], 0, 0, 0);
    __syncthreads();
  }
#endif

  int colb = (int)n0 + wn + r15;
  int rowb = (int)m0 + wm + cc * 4;
#pragma unroll
  for (int i = 0; i < 4; i++){
#pragma unroll
    for (int j = 0; j < 4; j++){
      int col = colb + j*16;
#pragma unroll
      for (int r = 0; r < 4; r++){
        int row = rowb + i*16 + r;
        float v = acc[i][j][r];
        if constexpr (EP == EP_B){
          g.Cb[coff + (long)row * g.ldc + col] = f2b(v);
        } else if constexpr (EP == EP_GELU){
          g.Cb[coff + (long)row * g.ldc + col] = f2b(gelu_f(v));
        } else if constexpr (EP == EP_BIAS_GELU){
          v = gelu_f(v + g.bias[col]);
          g.Cb[coff + (long)row * g.ldc + col] = f2b(v);
        } else if constexpr (EP == EP_BIAS_RESB){
          v += g.bias[col] + b2f(g.res[(long)row * g.ldc + col]);
          g.Cb[coff + (long)row * g.ldc + col] = f2b(v);
        } else if constexpr (EP == EP_SCALE){
          g.Cb[coff + (long)row * g.ldc + col] = f2b(v * g.scale);
        } else if constexpr (EP == EP_F32){
          g.Cf[coff + (long)row * g.ldc + col] = v;
        } else { // EP_QP_GELU: rank-2 update for [x, query_pos] concat (Wh1 rows 256,257)
          v += g.qp[(long)row*2] * g.wtail[col] + g.qp[(long)row*2+1] * g.wtail[256+col];
          g.Cb[coff + (long)row * g.ldc + col] = f2b(gelu_f(v));
        }
      }
    }
  }
}

// ---------------- host ----------------

extern "C" void kernel_launch(void* const* d_in, const int* in_sizes, int n_in,
                              void* d_out, int out_size, void* d_ws, size_t ws_size,
                              hipStream_t stream){
  const float* z   = (const float*)d_in[0];
  const float* qp  = (const float*)d_in[1];
  const float* cp  = (const float*)d_in[2];
  const float* Bff = (const float*)d_in[3];
  const float* Wc1 = (const float*)d_in[4];
  const float* Wc2 = (const float*)d_in[5];
  const float* Wq  = (const float*)d_in[6];
  const float* Wkv = (const float*)d_in[7];
  const float* Wo  = (const float*)d_in[8];
  const float* bo  = (const float*)d_in[9];
  const float* Wf1 = (const float*)d_in[10];
  const float* bf1 = (const float*)d_in[11];
  const float* Wf2 = (const float*)d_in[12];
  const float* bf2 = (const float*)d_in[13];
  const float* Wh1 = (const float*)d_in[14];
  const float* Wh2 = (const float*)d_in[15];
  const float* Wh3 = (const float*)d_in[16];
  const float* bh3 = (const float*)d_in[17];
  float* out = (float*)d_out;
  (void)in_sizes; (void)n_in; (void)out_size;

  size_t mb = ws_size >> 20;
  int C;
  if      (mb >= 264) C = 1;
  else if (mb >= 168) C = 2;
  else if (mb >= 120) C = 4;
  else                C = 8;
  const int NB = 8 / C;
  const long R = (long)NB * 4096;

  char* ws = (char*)d_ws;
  const size_t MB = 1024*1024;
  u16* WqT  = (u16*)(ws + 0);
  u16* WkvT = (u16*)(ws + 512*1024);
  u16* WoT  = (u16*)(ws + 1536*1024);
  u16* Wc1T = (u16*)(ws + 2048*1024);
  u16* Wc2T = (u16*)(ws + (2048+128)*1024);
  u16* Wf1T = (u16*)(ws + (2048+256)*1024);
  u16* Wf2T = (u16*)(ws + (2048+384)*1024);
  u16* Wh1T = (u16*)(ws + (2048+512)*1024);
  u16* Wh2T = (u16*)(ws + (2048+640)*1024);
  u16* R1 = (u16*)(ws + 4*MB);    // X0b -> X2b
  u16* R2 = (u16*)(ws + 20*MB);   // Tb -> H1b
  u16* R3 = (u16*)(ws + 36*MB);   // Xb -> X3
  u16* R4 = (u16*)(ws + 52*MB);   // Zb -> H2b
  u16* kvT = (u16*)(ws + 68*MB);  // 4MB: 32 mats [e=256][d=256]
  u16* BIG1 = (u16*)(ws + 72*MB);                     // kv f32 partials -> Qb
  u16* BIG2 = (u16*)((char*)BIG1 + (size_t)NB*8*MB);  // Kt -> ATTb
  u16* BIG3 = (u16*)((char*)BIG2 + (size_t)NB*8*MB);  // Vt

  u16* X0b = R1; u16* X2b = R1;
  u16* Tb  = R2; u16* H1b = R2;
  u16* Xb  = R3;
  u16* Zb  = R4; u16* H2b = R4;

  auto G = [&](int ep, const u16* A, const u16* B, u16* Cb, float* Cf,
               const float* bias, const u16* res, const float* qq, const float* wtail,
               float scale, int M, int N, int K, int lda, int ldb, int ldc,
               int nz, int NLO, long sAh, long sAl, long sBh, long sBl, long sCh, long sCl){
    GArgs g;
    g.A=A; g.B=B; g.Cb=Cb; g.Cf=Cf; g.bias=bias; g.res=res; g.qp=qq; g.wtail=wtail;
    g.scale=scale; g.M=M; g.N=N; g.K=K; g.lda=lda; g.ldb=ldb; g.ldc=ldc; g.NLO=NLO;
    g.sAh=sAh; g.sAl=sAl; g.sBh=sBh; g.sBl=sBl; g.sCh=sCh; g.sCl=sCl;
    dim3 gr(M/128, N/128, nz); dim3 bl(256);
    switch(ep){
      case EP_B:          gemm_k<EP_B><<<gr,bl,0,stream>>>(g); break;
      case EP_GELU:       gemm_k<EP_GELU><<<gr,bl,0,stream>>>(g); break;
      case EP_BIAS_GELU:  gemm_k<EP_BIAS_GELU><<<gr,bl,0,stream>>>(g); break;
      case EP_BIAS_RESB:  gemm_k<EP_BIAS_RESB><<<gr,bl,0,stream>>>(g); break;
      case EP_SCALE:      gemm_k<EP_SCALE><<<gr,bl,0,stream>>>(g); break;
      case EP_QP_GELU:    gemm_k<EP_QP_GELU><<<gr,bl,0,stream>>>(g); break;
      case EP_F32:        gemm_k<EP_F32><<<gr,bl,0,stream>>>(g); break;
    }
  };

  // ---- merged prep: z cast + weight transposes + fourier
  {
    PrepArgs a;
    a.z = z; a.Zb = Zb; a.qp = qp; a.Bff = Bff; a.X0 = X0b;
    const float* Ws[9] = { Wq, Wkv, Wo, Wc1, Wc2, Wf1, Wf2, Wh1, Wh2 };
    u16* Wts[9] = { WqT, WkvT, WoT, Wc1T, Wc2T, Wf1T, Wf2T, Wh1T, Wh2T };
    int Ks[9] = { 256, 256, 1024, 256, 256, 256, 256, 256, 256 };
    int Ns[9] = { 1024, 2048, 256, 256, 256, 256, 256, 256, 128 };
    int off = 0;
    for (int i = 0; i < 9; i++){
      a.W[i] = Ws[i]; a.Wt[i] = Wts[i]; a.K[i] = Ks[i]; a.N[i] = Ns[i];
      a.boff[i] = off; off += Ks[i]*Ns[i]/256;
    }
    a.boff[9] = off;
    a.castB = 8192; a.tcB = off;
    k_prep<<<dim3(8192 + off + 16384), dim3(256), 0, stream>>>(a);
  }

  // ---- query trunk
  G(EP_GELU, X0b, Wc1T, Tb, 0, 0,0,0,0, 1.f, 32768,256,256, 256,256,256, 1,1, 0,0,0,0,0,0);
  G(EP_B,    Tb,  Wc2T, Xb, 0, 0,0,0,0, 1.f, 32768,256,256, 256,256,256, 1,1, 0,0,0,0,0,0);

  // ---- attention arm, per batch-chunk
  for (int c = 0; c < C; c++){
    long row0 = (long)c * R;
    const u16* Zc = Zb + row0 * 256;
    // K+V fused: z@Wkv -> rot(K)/norm -> Kt, Vt  [mat][d][n]
    gemm_fuse<0><<<dim3(8, (int)(R/128)), dim3(256), 0, stream>>>(Zc, WkvT, BIG2, BIG3, cp + row0*2);
    // kv^T[e][d] = sum_n V[n,e] K[n,d], split-K 4 -> f32 partials, then reduce to bf16
    G(EP_F32, BIG3, BIG2, 0, (float*)BIG1, 0,0,0,0, 1.f,
      256,256,1024, 4096,4096,256, 4*NB*4, NB*4,
      1024,1048576, 1024,1048576, (long)NB*4*65536,65536);
    k_red<<<dim3(NB*256), dim3(256), 0, stream>>>((float*)BIG1, kvT + (long)c*NB*4*65536, (long)NB*4*65536);
    // Q = rot(x@Wq) -> [n][h*256+d]
    gemm_fuse<1><<<dim3(4, (int)(R/128)), dim3(256), 0, stream>>>(Xb + row0*256, WqT, BIG1, 0, qp + row0*2);
    // attn = q@kv * (1/nc)
    G(EP_SCALE, BIG1, kvT + (long)c*NB*4*65536, BIG2, 0, 0,0,0,0, 1.0f/4096.0f,
      4096,256,256, 1024,256,1024, NB*4,4, 4194304,256, 262144,65536, 4194304,256);
    // x2 = attn@Wo + bo + x
    G(EP_BIAS_RESB, BIG2, WoT, X2b + row0*256, 0, bo, Xb + row0*256, 0,0, 1.f,
      (int)R,256,1024, 1024,1024,256, 1,1, 0,0,0,0,0,0);
  }

  // ---- FF block + head MLP
  G(EP_BIAS_GELU, X2b, Wf1T, Tb, 0, bf1, 0,0,0, 1.f, 32768,256,256, 256,256,256, 1,1, 0,0,0,0,0,0);
  G(EP_BIAS_RESB, Tb, Wf2T, Xb, 0, bf2, X2b, 0,0, 1.f, 32768,256,256, 256,256,256, 1,1, 0,0,0,0,0,0);
  G(EP_QP_GELU, Xb, Wh1T, H1b, 0, 0,0, qp, Wh1 + 65536, 1.f, 32768,256,256, 256,256,256, 1,1, 0,0,0,0,0,0);
  G(EP_GELU, H1b, Wh2T, H2b, 0, 0,0,0,0, 1.f, 32768,128,256, 256,256,128, 1,1, 0,0,0,0,0,0);
  k_final<<<dim3(128), dim3(256), 0, stream>>>(H2b, Wh3, bh3, out);
}

// Round 9
// 550.397 us; speedup vs baseline: 2.0721x; 2.0721x over previous
//
#include <hip/hip_runtime.h>
#include <math.h>

// PointWiseDecoder2DSimple on MI355X (gfx950)
// b=8, nq=nc=4096, LATENT=256, HEADS=4, DH=256, INNER=1024.
// R9: revert launch_bounds to (256,2) (R8's (256,3) spilled acc -> 2x regress);
// algebraic collapse: x2 = q @ W2,  W2T = (Wo^T per-head) @ kv  (1.07 GF tiny GEMM)
// -> attn GEMM + ATTb intermediate deleted; 1/nc folded into k_red.

typedef unsigned short u16;
typedef __attribute__((ext_vector_type(4))) float f32x4;
typedef __attribute__((ext_vector_type(8))) short s16x8;
typedef __attribute__((ext_vector_type(8))) unsigned short u16x8;
typedef __attribute__((ext_vector_type(4))) unsigned short u16x4;

#define LOG2_1E4_D64 0.20762050593046013f  // log2(10000)/64

#define VMCNT(n) do{ asm volatile("s_waitcnt vmcnt(" #n ")" ::: "memory"); \
                     __builtin_amdgcn_sched_barrier(0); }while(0)
#define BARRIER() do{ __builtin_amdgcn_s_barrier(); \
                      __builtin_amdgcn_sched_barrier(0); }while(0)

__device__ __forceinline__ u16 f2b(float f){
  union { float f; unsigned u; } v; v.f = f;
  unsigned u = v.u;
  u += 0x7FFFu + ((u >> 16) & 1u);
  return (u16)(u >> 16);
}
__device__ __forceinline__ float b2f(u16 b){
  union { unsigned u; float f; } v; v.u = ((unsigned)b) << 16; return v.f;
}
__device__ __forceinline__ float gelu_f(float x){
  return 0.5f * x * (1.0f + erff(x * 0.7071067811865475f));
}

#if __has_builtin(__builtin_amdgcn_global_load_lds)
#define HAVE_GLL 1
typedef const __attribute__((address_space(1))) void* as1cv;
typedef __attribute__((address_space(3))) void* as3v;
__device__ __forceinline__ void gload16(const void* g, void* l){
  __builtin_amdgcn_global_load_lds((as1cv)g, (as3v)l, 16, 0, 0);
}
#else
#define HAVE_GLL 0
#endif

// ---------------- merged prep: z-cast + 9 weight transposes + fourier ----------------

struct PrepArgs {
  const float* z; u16* Zb;
  const float* qp; const float* Bff; u16* X0;
  const float* W[9]; u16* Wt[9];
  int K[9]; int N[9]; int boff[10];
  int castB, tcB;
};
__global__ __launch_bounds__(256) void k_prep(PrepArgs a){
  int b = blockIdx.x, tid = threadIdx.x;
  if (b < a.castB){
    long i = (long)b * 256 + tid;
    float4 f = ((const float4*)a.z)[i];
    u16x4 o = { f2b(f.x), f2b(f.y), f2b(f.z), f2b(f.w) };
    ((u16x4*)a.Zb)[i] = o;
  } else if (b < a.castB + a.tcB){
    int bb = b - a.castB;
    int w = 0;
    while (bb >= a.boff[w+1]) w++;
    int idx = (bb - a.boff[w]) * 256 + tid;
    int K = a.K[w], N = a.N[w];
    int n = idx / K, k = idx - n * K;
    a.Wt[w][idx] = f2b(a.W[w][(long)k * N + n]);
  } else {
    int bb = b - a.castB - a.tcB;
    long r = (long)bb * 2 + (tid >> 7);
    int j = tid & 127;
    float qx = a.qp[r*2], qy = a.qp[r*2+1];
    float ff = 6.283185307179586f * (qx * a.Bff[j] + qy * a.Bff[128 + j]);
    a.X0[r*256 + j]       = f2b(sinf(ff));
    a.X0[r*256 + 128 + j] = f2b(cosf(ff));
  }
}

// split-K reduce with scale: kv[i] = bf16(scale * sum_sp p[sp][i]), SPL=4
__global__ __launch_bounds__(256) void k_red(const float* __restrict__ p, u16* __restrict__ out,
                                             long stride, float scale){
  long i = (long)blockIdx.x * 256 + threadIdx.x;
  f32x4 s = ((const f32x4*)p)[i];
  s += ((const f32x4*)(p + stride))[i];
  s += ((const f32x4*)(p + 2*stride))[i];
  s += ((const f32x4*)(p + 3*stride))[i];
  u16x4 o = { f2b(s[0]*scale), f2b(s[1]*scale), f2b(s[2]*scale), f2b(s[3]*scale) };
  ((u16x4*)out)[i] = o;
}

// final head: out = H2 @ Wh3 + bh3  (N=3, K=128), fp32
__global__ __launch_bounds__(256) void k_final(const u16* __restrict__ H2, const float* __restrict__ Wh3,
                                               const float* __restrict__ bh3, float* __restrict__ out){
  long r = (long)blockIdx.x * 256 + threadIdx.x;
  float a0 = bh3[0], a1 = bh3[1], a2 = bh3[2];
  const u16x8* hrow = (const u16x8*)(H2 + r*128);
#pragma unroll
  for (int c8 = 0; c8 < 16; c8++){
    u16x8 hv = hrow[c8];
#pragma unroll
    for (int e = 0; e < 8; e++){
      float f = b2f(hv[e]);
      int k = c8*8 + e;
      a0 += f * Wh3[k*3];
      a1 += f * Wh3[k*3+1];
      a2 += f * Wh3[k*3+2];
    }
  }
  out[r*3] = a0; out[r*3+1] = a1; out[r*3+2] = a2;
}

// ---------------- fused projection GEMM: one head per block-x ----------------
// C[128x256] = A[128,256] * Bh[256,256]^T  then per MODE:
//   0: KV combined — x<4: K-head (rotary+norm+T-store), x>=4: V-head (norm+T-store)
//   1: Q — rotary + coalesced store [n][x*256+d] via TB bounce
// Pipelined staging (counted vmcnt(6), 2-deep), both-sides XOR swizzle.

template<int MODE>
__global__ __launch_bounds__(256, 2)
void gemm_fuse(const u16* __restrict__ A, const u16* __restrict__ Bw,
               u16* __restrict__ outK, u16* __restrict__ outV,
               const float* __restrict__ pos){
  __shared__ char smem[49152];
  u16* AsB = (u16*)smem;            // [2][128*32]
  u16* BsB = (u16*)(smem + 16384);  // [2][256*32]

  int tid  = threadIdx.x;
  int lane = tid & 63;
  int wave = tid >> 6;
  int wm = (wave & 1) << 6;
  int wn = (wave >> 1) << 7;
  int whalf = wave >> 1;
  int yb = blockIdx.x;
  int h  = yb & 3;
  bool isK = (MODE == 1) || (yb < 4);
  long m0 = (long)blockIdx.y * 128;

  int r15 = lane & 15;
  int cc  = lane >> 4;
  int fsw = (cc ^ ((r15 >> 1) & 3)) * 8;              // read-side swizzle
  const u16* Bh = Bw + (long)yb * 65536;

  f32x4 acc[4][8];
#pragma unroll
  for (int i = 0; i < 4; i++)
#pragma unroll
    for (int j = 0; j < 8; j++)
      acc[i][j] = f32x4{0.f, 0.f, 0.f, 0.f};

#if HAVE_GLL
  int srow  = lane >> 2;
  int scolS = ((lane & 3) ^ ((lane >> 3) & 3)) * 8;   // pre-swizzled global source
  int aRow[2], bRow[4];
  const u16 *gA[2], *gB[4];
#pragma unroll
  for (int t = 0; t < 2; t++){
    aRow[t] = (wave*2 + t) * 16;
    gA[t] = A + (m0 + aRow[t] + srow) * 256 + scolS;
  }
#pragma unroll
  for (int t = 0; t < 4; t++){
    bRow[t] = (wave*4 + t) * 16;
    gB[t] = Bh + (bRow[t] + srow) * 256 + scolS;
  }
  auto stage = [&](int buf, int kk){
    u16* ab = AsB + buf*4096;
    u16* bb = BsB + buf*8192;
#pragma unroll
    for (int t = 0; t < 2; t++) gload16(gA[t] + kk*32, ab + aRow[t]*32);
#pragma unroll
    for (int t = 0; t < 4; t++) gload16(gB[t] + kk*32, bb + bRow[t]*32);
  };
  auto compute = [&](int buf){
    const u16* ab = AsB + buf*4096;
    const u16* bb = BsB + buf*8192;
    s16x8 af[4], bf[8];
#pragma unroll
    for (int i = 0; i < 4; i++) af[i] = *(const s16x8*)&ab[(wm + i*16 + r15)*32 + fsw];
#pragma unroll
    for (int j = 0; j < 8; j++) bf[j] = *(const s16x8*)&bb[(wn + j*16 + r15)*32 + fsw];
#pragma unroll
    for (int i = 0; i < 4; i++)
#pragma unroll
      for (int j = 0; j < 8; j++)
        acc[i][j] = __builtin_amdgcn_mfma_f32_16x16x32_bf16(af[i], bf[j], acc[i][j], 0, 0, 0);
  };

  stage(0, 0);
  stage(1, 1);
  int cur = 0;
  for (int t = 0; t < 7; t++){
    VMCNT(6);
    BARRIER();
    compute(cur);
    __builtin_amdgcn_sched_barrier(0);
    BARRIER();
    if (t + 2 < 8) stage(cur, t + 2);
    cur ^= 1;
  }
  VMCNT(0);
  BARRIER();
  compute(cur);
#else
  int sm = tid >> 2, sc = tid & 3;
  for (int k0 = 0; k0 < 256; k0 += 32){
    u16x8 va  = *(const u16x8*)(A + (m0 + sm)*256 + sc*8 + k0);
    u16x8 va1 = *(const u16x8*)(A + (m0 + sm + 64)*256 + sc*8 + k0);
    u16x8 vb0 = *(const u16x8*)(Bh + (sm      )*256 + sc*8 + k0);
    u16x8 vb1 = *(const u16x8*)(Bh + (sm + 64 )*256 + sc*8 + k0);
    u16x8 vb2 = *(const u16x8*)(Bh + (sm + 128)*256 + sc*8 + k0);
    u16x8 vb3 = *(const u16x8*)(Bh + (sm + 192)*256 + sc*8 + k0);
    __syncthreads();
    *(u16x8*)&AsB[sm*32 + sc*8] = va;
    *(u16x8*)&AsB[(sm+64)*32 + sc*8] = va1;
    *(u16x8*)&BsB[sm*32 + sc*8] = vb0;
    *(u16x8*)&BsB[(sm+64)*32 + sc*8] = vb1;
    *(u16x8*)&BsB[(sm+128)*32 + sc*8] = vb2;
    *(u16x8*)&BsB[(sm+192)*32 + sc*8] = vb3;
    __syncthreads();
    s16x8 af[4], bf[8];
#pragma unroll
    for (int i = 0; i < 4; i++) af[i] = *(const s16x8*)&AsB[(wm + i*16 + r15)*32 + cc*8];
#pragma unroll
    for (int j = 0; j < 8; j++) bf[j] = *(const s16x8*)&BsB[(wn + j*16 + r15)*32 + cc*8];
#pragma unroll
    for (int i = 0; i < 4; i++)
#pragma unroll
      for (int j = 0; j < 8; j++)
        acc[i][j] = __builtin_amdgcn_mfma_f32_16x16x32_bf16(af[i], bf[j], acc[i][j], 0, 0, 0);
    __syncthreads();
  }
#endif

  // ---- rotary: pair acc[i][j] <-> acc[i][j+4]; axis = whalf
  if (isK){
    float invf4[4];
#pragma unroll
    for (int jl = 0; jl < 4; jl++)
      invf4[jl] = 1024.0f * exp2f(-(float)(jl*16 + r15) * LOG2_1E4_D64);
#pragma unroll
    for (int i = 0; i < 4; i++){
#pragma unroll
      for (int r = 0; r < 4; r++){
        long n = m0 + wm + i*16 + cc*4 + r;
        float p = pos[n*2 + whalf];
#pragma unroll
        for (int jl = 0; jl < 4; jl++){
          float a = p * invf4[jl];
          float s = __sinf(a), c = __cosf(a);
          float t0 = acc[i][jl][r], t1 = acc[i][jl+4][r];
          acc[i][jl][r]   = t0*c - t1*s;
          acc[i][jl+4][r] = t1*c + t0*s;
        }
      }
    }
  }

  if constexpr (MODE == 1){
    // Q: coalesced store via TB bounce (XOR swizzle, chunk-XOR + elem-permute)
    u16* TB = (u16*)smem;   // 32KB
    __syncthreads();        // staging LDS dead before alias reuse
    long rowg = m0;
#pragma unroll
    for (int p = 0; p < 2; p++){
      if ((wave & 1) == p){
#pragma unroll
        for (int i = 0; i < 4; i++)
#pragma unroll
          for (int j = 0; j < 8; j++)
#pragma unroll
            for (int r = 0; r < 4; r++){
              int nl = i*16 + cc*4 + r;
              int d  = wn + j*16 + r15;
              TB[nl*256 + (d ^ ((nl>>2)<<1))] = f2b(acc[i][j][r]);
            }
      }
      __syncthreads();
      {
        int nl = tid >> 2;
        int cb = (tid & 3) * 8;
        int sw = (nl >> 2) << 1;
        int swHi = sw & ~7, swLo = sw & 7;
        u16* orow = outK + (rowg + p*64 + nl) * 1024 + yb*256;
#pragma unroll
        for (int c8 = 0; c8 < 8; c8++){
          int cblk = cb + c8*32;
          u16x8 vv = *(const u16x8*)&TB[nl*256 + (cblk ^ swHi)];
          u16x8 ov;
#pragma unroll
          for (int e = 0; e < 8; e++) ov[e] = vv[e ^ swLo];
          *(u16x8*)(orow + cblk) = ov;
        }
      }
      __syncthreads();
    }
  } else {
    // ---- inst_norm over 256 head dims, then transposed store [mat][d][n]
    u16*   TB  = (u16*)smem;               // 32KB
    float* PS1 = (float*)(smem + 32768);
    float* PS2 = (float*)(smem + 33792);

    __syncthreads();   // all waves done with staging LDS before reuse (race fix)

#pragma unroll
    for (int i = 0; i < 4; i++){
#pragma unroll
      for (int r = 0; r < 4; r++){
        float s1 = 0.f, s2 = 0.f;
#pragma unroll
        for (int j = 0; j < 8; j++){
          float v = acc[i][j][r];
          s1 += v; s2 += v*v;
        }
#pragma unroll
        for (int m = 1; m < 16; m <<= 1){
          s1 += __shfl_xor(s1, m, 64);
          s2 += __shfl_xor(s2, m, 64);
        }
        int rowid = (wave&1)*64 + i*16 + cc*4 + r;
        if (r15 == 0){ PS1[whalf*128 + rowid] = s1; PS2[whalf*128 + rowid] = s2; }
      }
    }
    __syncthreads();
#pragma unroll
    for (int i = 0; i < 4; i++){
#pragma unroll
      for (int r = 0; r < 4; r++){
        int rowid = (wave&1)*64 + i*16 + cc*4 + r;
        float s1 = PS1[rowid] + PS1[128 + rowid];
        float s2 = PS2[rowid] + PS2[128 + rowid];
        float mu  = s1 * 0.00390625f;
        float var = s2 * 0.00390625f - mu*mu;
        float inv = 1.0f / sqrtf(var + 1e-5f);
#pragma unroll
        for (int j = 0; j < 8; j++)
          acc[i][j][r] = (acc[i][j][r] - mu) * inv;
      }
    }
    __syncthreads();

    u16* outp = isK ? outK : outV;
    int bb  = (int)(m0 >> 12);
    int nn0 = (int)(m0 & 4095);
    long matbase = ((long)(bb*4 + h) * 256) * 4096;
#pragma unroll
    for (int p = 0; p < 2; p++){
      if ((wave & 1) == p){
#pragma unroll
        for (int i = 0; i < 4; i++)
#pragma unroll
          for (int j = 0; j < 8; j++)
#pragma unroll
            for (int r = 0; r < 4; r++){
              int nl = i*16 + cc*4 + r;
              int d  = wn + j*16 + r15;
              TB[nl*256 + (d ^ ((nl>>2)<<1))] = f2b(acc[i][j][r]);
            }
      }
      __syncthreads();
      {
        int n4 = (lane & 15) * 4;
        int sw = (lane & 15) << 1;
#pragma unroll
        for (int rnd = 0; rnd < 16; rnd++){
          int d = rnd*16 + wave*4 + (lane >> 4);
          u16x4 vv;
#pragma unroll
          for (int jj = 0; jj < 4; jj++) vv[jj] = TB[(n4+jj)*256 + (d ^ sw)];
          *(u16x4*)(outp + matbase + (long)d*4096 + nn0 + p*64 + n4) = vv;
        }
      }
      __syncthreads();
    }
  }
}

// ---------------- generic GEMM: C = A[M,K] * B[N,K]^T, 128x128 tile ----------------

enum { EP_B = 0, EP_GELU = 1, EP_BIAS_GELU = 2, EP_BIAS_RESB = 3, EP_QP_GELU = 4, EP_F32 = 5 };

struct GArgs {
  const u16* A; const u16* B;
  u16* Cb; float* Cf;
  const float* bias; const u16* res; const float* qp; const float* wtail;
  int M, N, K, lda, ldb, ldc, NLO;
  long sAh, sAl, sBh, sBl, sCh, sCl;
};

template<int EP>
__global__ __launch_bounds__(256, 2)
void gemm_k(GArgs g){
  int z = blockIdx.z;
  int zh = z / g.NLO, zl = z - zh * g.NLO;
  const u16* A = g.A + (long)zh * g.sAh + (long)zl * g.sAl;
  const u16* B = g.B + (long)zh * g.sBh + (long)zl * g.sBl;
  long coff = (long)zh * g.sCh + (long)zl * g.sCl;

  __shared__ u16 As[2][128*32];
  __shared__ u16 Bs[2][128*32];

  int tid  = threadIdx.x;
  int lane = tid & 63;
  int wave = tid >> 6;
  int wm = (wave & 1) << 6;
  int wn = (wave >> 1) << 6;
  long m0 = (long)blockIdx.x * 128;
  long n0 = (long)blockIdx.y * 128;

  int r15 = lane & 15;
  int cc  = lane >> 4;
  int fsw = (cc ^ ((r15 >> 1) & 3)) * 8;

  f32x4 acc[4][4];
#pragma unroll
  for (int i = 0; i < 4; i++)
#pragma unroll
    for (int j = 0; j < 4; j++)
      acc[i][j] = f32x4{0.f, 0.f, 0.f, 0.f};

#if HAVE_GLL
  int srow  = lane >> 2;
  int scolS = ((lane & 3) ^ ((lane >> 3) & 3)) * 8;
  int aRow[2];
  const u16 *gA[2], *gB[2];
#pragma unroll
  for (int t = 0; t < 2; t++){
    aRow[t] = (wave*2 + t) * 16;
    gA[t] = A + (m0 + aRow[t] + srow) * g.lda + scolS;
    gB[t] = B + (n0 + aRow[t] + srow) * g.ldb + scolS;
  }
  auto stage = [&](int buf, int kk){
#pragma unroll
    for (int t = 0; t < 2; t++){
      gload16(gA[t] + kk*32, &As[buf][aRow[t]*32]);
      gload16(gB[t] + kk*32, &Bs[buf][aRow[t]*32]);
    }
  };
  auto compute = [&](int buf){
    s16x8 af[4], bf[4];
#pragma unroll
    for (int i = 0; i < 4; i++) af[i] = *(const s16x8*)&As[buf][(wm + i*16 + r15)*32 + fsw];
#pragma unroll
    for (int i = 0; i < 4; i++) bf[i] = *(const s16x8*)&Bs[buf][(wn + i*16 + r15)*32 + fsw];
#pragma unroll
    for (int i = 0; i < 4; i++)
#pragma unroll
      for (int j = 0; j < 4; j++)
        acc[i][j] = __builtin_amdgcn_mfma_f32_16x16x32_bf16(af[i], bf[j], acc[i][j], 0, 0, 0);
  };

  int nt = g.K >> 5;
  stage(0, 0);
  stage(1, 1);
  int cur = 0;
  for (int t = 0; t < nt - 1; t++){
    VMCNT(4);
    BARRIER();
    compute(cur);
    __builtin_amdgcn_sched_barrier(0);
    BARRIER();
    if (t + 2 < nt) stage(cur, t + 2);
    cur ^= 1;
  }
  VMCNT(0);
  BARRIER();
  compute(cur);
#else
  int sm  = tid >> 2;
  int sc  = tid & 3;
  for (int k0 = 0; k0 < g.K; k0 += 32){
    u16x8 va0 = *(const u16x8*)(A + (m0 + sm )*g.lda + sc*8 + k0);
    u16x8 va1 = *(const u16x8*)(A + (m0 + sm + 64)*g.lda + sc*8 + k0);
    u16x8 vb0 = *(const u16x8*)(B + (n0 + sm )*g.ldb + sc*8 + k0);
    u16x8 vb1 = *(const u16x8*)(B + (n0 + sm + 64)*g.ldb + sc*8 + k0);
    __syncthreads();
    *(u16x8*)&As[0][sm*32 + sc*8] = va0;
    *(u16x8*)&As[0][(sm+64)*32 + sc*8] = va1;
    *(u16x8*)&Bs[0][sm*32 + sc*8] = vb0;
    *(u16x8*)&Bs[0][(sm+64)*32 + sc*8] = vb1;
    __syncthreads();
    s16x8 af[4], bf[4];
#pragma unroll
    for (int i = 0; i < 4; i++) af[i] = *(const s16x8*)&As[0][(wm + i*16 + r15)*32 + cc*8];
#pragma unroll
    for (int i = 0; i < 4; i++) bf[i] = *(const s16x8*)&Bs[0][(wn + i*16 + r15)*32 + cc*8];
#pragma unroll
    for (int i = 0; i < 4; i++)
#pragma unroll
      for (int j = 0; j < 4; j++)
        acc[i][j] = __builtin_amdgcn_mfma_f32_16x16x32_bf16(af[i], bf[j], acc[i][j], 0, 0, 0);
    __syncthreads();
  }
#endif

  int colb = (int)n0 + wn + r15;
  int rowb = (int)m0 + wm + cc * 4;
#pragma unroll
  for (int i = 0; i < 4; i++){
#pragma unroll
    for (int j = 0; j < 4; j++){
      int col = colb + j*16;
#pragma unroll
      for (int r = 0; r < 4; r++){
        int row = rowb + i*16 + r;
        float v = acc[i][j][r];
        if constexpr (EP == EP_B){
          g.Cb[coff + (long)row * g.ldc + col] = f2b(v);
        } else if constexpr (EP == EP_GELU){
          g.Cb[coff + (long)row * g.ldc + col] = f2b(gelu_f(v));
        } else if constexpr (EP == EP_BIAS_GELU){
          v = gelu_f(v + g.bias[col]);
          g.Cb[coff + (long)row * g.ldc + col] = f2b(v);
        } else if constexpr (EP == EP_BIAS_RESB){
          v += g.bias[col] + b2f(g.res[coff + (long)row * g.ldc + col]);
          g.Cb[coff + (long)row * g.ldc + col] = f2b(v);
        } else if constexpr (EP == EP_F32){
          g.Cf[coff + (long)row * g.ldc + col] = v;
        } else { // EP_QP_GELU: rank-2 update for [x, query_pos] concat (Wh1 rows 256,257)
          v += g.qp[(long)row*2] * g.wtail[col] + g.qp[(long)row*2+1] * g.wtail[256+col];
          g.Cb[coff + (long)row * g.ldc + col] = f2b(gelu_f(v));
        }
      }
    }
  }
}

// ---------------- host ----------------

extern "C" void kernel_launch(void* const* d_in, const int* in_sizes, int n_in,
                              void* d_out, int out_size, void* d_ws, size_t ws_size,
                              hipStream_t stream){
  const float* z   = (const float*)d_in[0];
  const float* qp  = (const float*)d_in[1];
  const float* cp  = (const float*)d_in[2];
  const float* Bff = (const float*)d_in[3];
  const float* Wc1 = (const float*)d_in[4];
  const float* Wc2 = (const float*)d_in[5];
  const float* Wq  = (const float*)d_in[6];
  const float* Wkv = (const float*)d_in[7];
  const float* Wo  = (const float*)d_in[8];
  const float* bo  = (const float*)d_in[9];
  const float* Wf1 = (const float*)d_in[10];
  const float* bf1 = (const float*)d_in[11];
  const float* Wf2 = (const float*)d_in[12];
  const float* bf2 = (const float*)d_in[13];
  const float* Wh1 = (const float*)d_in[14];
  const float* Wh2 = (const float*)d_in[15];
  const float* Wh3 = (const float*)d_in[16];
  const float* bh3 = (const float*)d_in[17];
  float* out = (float*)d_out;
  (void)in_sizes; (void)n_in; (void)out_size;

  size_t mb = ws_size >> 20;
  int C;
  if      (mb >= 268) C = 1;
  else if (mb >= 172) C = 2;
  else if (mb >= 124) C = 4;
  else                C = 8;
  const int NB = 8 / C;
  const long R = (long)NB * 4096;

  char* ws = (char*)d_ws;
  const size_t MB = 1024*1024;
  u16* WqT  = (u16*)(ws + 0);
  u16* WkvT = (u16*)(ws + 512*1024);
  u16* WoT  = (u16*)(ws + 1536*1024);
  u16* Wc1T = (u16*)(ws + 2048*1024);
  u16* Wc2T = (u16*)(ws + (2048+128)*1024);
  u16* Wf1T = (u16*)(ws + (2048+256)*1024);
  u16* Wf2T = (u16*)(ws + (2048+384)*1024);
  u16* Wh1T = (u16*)(ws + (2048+512)*1024);
  u16* Wh2T = (u16*)(ws + (2048+640)*1024);
  u16* R1 = (u16*)(ws + 4*MB);    // X0b -> X2b
  u16* R2 = (u16*)(ws + 20*MB);   // Tb -> H1b
  u16* R3 = (u16*)(ws + 36*MB);   // Xb -> X3
  u16* R4 = (u16*)(ws + 52*MB);   // Zb -> H2b
  u16* kvB = (u16*)(ws + 68*MB);  // 4MB: 32 mats kv [d=256][e=256]
  u16* W2T = (u16*)(ws + 72*MB);  // 4MB: 8 batches [c=256][k=1024]
  u16* BIG1 = (u16*)(ws + 76*MB);                     // kv f32 partials -> Qb
  u16* BIG2 = (u16*)((char*)BIG1 + (size_t)NB*8*MB);  // Kt
  u16* BIG3 = (u16*)((char*)BIG2 + (size_t)NB*8*MB);  // Vt

  u16* X0b = R1; u16* X2b = R1;
  u16* Tb  = R2; u16* H1b = R2;
  u16* Xb  = R3;
  u16* Zb  = R4; u16* H2b = R4;

  auto G = [&](int ep, const u16* A, const u16* B, u16* Cb, float* Cf,
               const float* bias, const u16* res, const float* qq, const float* wtail,
               int M, int N, int K, int lda, int ldb, int ldc,
               int nz, int NLO, long sAh, long sAl, long sBh, long sBl, long sCh, long sCl){
    GArgs g;
    g.A=A; g.B=B; g.Cb=Cb; g.Cf=Cf; g.bias=bias; g.res=res; g.qp=qq; g.wtail=wtail;
    g.M=M; g.N=N; g.K=K; g.lda=lda; g.ldb=ldb; g.ldc=ldc; g.NLO=NLO;
    g.sAh=sAh; g.sAl=sAl; g.sBh=sBh; g.sBl=sBl; g.sCh=sCh; g.sCl=sCl;
    dim3 gr(M/128, N/128, nz); dim3 bl(256);
    switch(ep){
      case EP_B:          gemm_k<EP_B><<<gr,bl,0,stream>>>(g); break;
      case EP_GELU:       gemm_k<EP_GELU><<<gr,bl,0,stream>>>(g); break;
      case EP_BIAS_GELU:  gemm_k<EP_BIAS_GELU><<<gr,bl,0,stream>>>(g); break;
      case EP_BIAS_RESB:  gemm_k<EP_BIAS_RESB><<<gr,bl,0,stream>>>(g); break;
      case EP_QP_GELU:    gemm_k<EP_QP_GELU><<<gr,bl,0,stream>>>(g); break;
      case EP_F32:        gemm_k<EP_F32><<<gr,bl,0,stream>>>(g); break;
    }
  };

  // ---- merged prep: z cast + weight transposes + fourier
  {
    PrepArgs a;
    a.z = z; a.Zb = Zb; a.qp = qp; a.Bff = Bff; a.X0 = X0b;
    const float* Ws[9] = { Wq, Wkv, Wo, Wc1, Wc2, Wf1, Wf2, Wh1, Wh2 };
    u16* Wts[9] = { WqT, WkvT, WoT, Wc1T, Wc2T, Wf1T, Wf2T, Wh1T, Wh2T };
    int Ks[9] = { 256, 256, 1024, 256, 256, 256, 256, 256, 256 };
    int Ns[9] = { 1024, 2048, 256, 256, 256, 256, 256, 256, 128 };
    int off = 0;
    for (int i = 0; i < 9; i++){
      a.W[i] = Ws[i]; a.Wt[i] = Wts[i]; a.K[i] = Ks[i]; a.N[i] = Ns[i];
      a.boff[i] = off; off += Ks[i]*Ns[i]/256;
    }
    a.boff[9] = off;
    a.castB = 8192; a.tcB = off;
    k_prep<<<dim3(8192 + off + 16384), dim3(256), 0, stream>>>(a);
  }

  // ---- query trunk
  G(EP_GELU, X0b, Wc1T, Tb, 0, 0,0,0,0, 32768,256,256, 256,256,256, 1,1, 0,0,0,0,0,0);
  G(EP_B,    Tb,  Wc2T, Xb, 0, 0,0,0,0, 32768,256,256, 256,256,256, 1,1, 0,0,0,0,0,0);

  // ---- attention arm, per batch-chunk
  for (int c = 0; c < C; c++){
    long row0 = (long)c * R;
    const u16* Zc = Zb + row0 * 256;
    u16* kvC  = kvB + (long)c*NB*262144;
    u16* W2Tc = W2T + (long)c*NB*262144;
    // K+V fused: z@Wkv -> rot(K)/norm -> Kt, Vt  [mat][d][n]
    gemm_fuse<0><<<dim3(8, (int)(R/128)), dim3(256), 0, stream>>>(Zc, WkvT, BIG2, BIG3, cp + row0*2);
    // kv[d][e] = sum_n K[n,d] V[n,e], split-K 4 -> f32 partials, then reduce(*1/nc) to bf16
    G(EP_F32, BIG2, BIG3, 0, (float*)BIG1, 0,0,0,0,
      256,256,1024, 4096,4096,256, 4*NB*4, NB*4,
      1024,1048576, 1024,1048576, (long)NB*4*65536,65536);
    k_red<<<dim3(NB*256), dim3(256), 0, stream>>>((float*)BIG1, kvC, (long)NB*4*65536, 1.0f/4096.0f);
    // W2T[c_ch][h*256+d] = sum_e Wo[h*256+e, c_ch] * kv[d,e]   (per batch)
    G(EP_B, WoT, kvC, W2Tc, 0, 0,0,0,0,
      256,256,256, 1024,256,1024, NB*4, 4,
      0,256, 262144,65536, 262144,256);
    // Q = rot(x@Wq) -> [n][h*256+d]
    gemm_fuse<1><<<dim3(4, (int)(R/128)), dim3(256), 0, stream>>>(Xb + row0*256, WqT, BIG1, 0, qp + row0*2);
    // x2 = q @ W2T^T + bo + x   (batched per batch; res/C use coff)
    G(EP_BIAS_RESB, BIG1, W2Tc, X2b + row0*256, 0, bo, Xb + row0*256, 0,0,
      4096,256,1024, 1024,1024,256, NB, 1,
      4194304,0, 262144,0, 1048576,0);
  }

  // ---- FF block + head MLP
  G(EP_BIAS_GELU, X2b, Wf1T, Tb, 0, bf1, 0,0,0, 32768,256,256, 256,256,256, 1,1, 0,0,0,0,0,0);
  G(EP_BIAS_RESB, Tb, Wf2T, Xb, 0, bf2, X2b, 0,0, 32768,256,256, 256,256,256, 1,1, 0,0,0,0,0,0);
  G(EP_QP_GELU, Xb, Wh1T, H1b, 0, 0,0, qp, Wh1 + 65536, 32768,256,256, 256,256,256, 1,1, 0,0,0,0,0,0);
  G(EP_GELU, H1b, Wh2T, H2b, 0, 0,0,0,0, 32768,128,256, 256,256,128, 1,1, 0,0,0,0,0,0);
  k_final<<<dim3(128), dim3(256), 0, stream>>>(H2b, Wh3, bh3, out);
}